// Round 2
// baseline (1142.440 us; speedup 1.0000x reference)
//
#include <hip/hip_runtime.h>
#include <math.h>

#define NBATCH 16
#define DDIM   256
#define TLEN   1500
#define NROWS  (NBATCH * TLEN)     // 24000
#define KBINS  1024
#define NQ     8
#define RPB    32                  // rows per block
#define QMAX   384

typedef float  f32x4  __attribute__((ext_vector_type(4)));
typedef short  short8 __attribute__((ext_vector_type(8)));
union Frag { uint4 u; short8 s; };

__device__ __forceinline__ unsigned cvtpk(float a, float b) {
    unsigned r;
    asm("v_cvt_pk_bf16_f32 %0, %1, %2" : "=v"(r) : "v"(a), "v"(b));
    return r;
}

// LDS-only barrier: waits ds ops, does NOT drain vmcnt -> global prefetch
// stays in flight across phase boundaries. All inter-wave comms here are LDS.
__device__ __forceinline__ void barrier_lds() {
    __builtin_amdgcn_sched_barrier(0);
    asm volatile("s_waitcnt lgkmcnt(0)" ::: "memory");
    __builtin_amdgcn_s_barrier();
    __builtin_amdgcn_sched_barrier(0);
}

// ---------------------------------------------------------------------------
// Kernel 1: cbsq[q][k] = numpy-pairwise sum(c*c) over D=256  (+ zero losses)
// ---------------------------------------------------------------------------
__global__ __launch_bounds__(256) void cbsq_kernel(const float* __restrict__ cb,
                                                   float* __restrict__ ws) {
    const int k = blockIdx.x * 256 + threadIdx.x;      // 0..8191
    if (blockIdx.x == 0 && threadIdx.x < NQ) ws[NQ * KBINS + threadIdx.x] = 0.f;
    if (k >= NQ * KBINS) return;
    const float* p = cb + (size_t)k * DDIM;
    float total = 0.f;
    #pragma unroll
    for (int h = 0; h < 2; ++h) {
        const float* ph = p + h * 128;
        float r[8];
        #pragma unroll
        for (int j = 0; j < 8; ++j) { float v = ph[j]; r[j] = __fmul_rn(v, v); }
        for (int i = 8; i < 128; i += 8) {
            #pragma unroll
            for (int j = 0; j < 8; ++j) {
                float v = ph[i + j];
                r[j] = __fadd_rn(r[j], __fmul_rn(v, v));
            }
        }
        float s = __fadd_rn(__fadd_rn(__fadd_rn(r[0], r[1]), __fadd_rn(r[2], r[3])),
                            __fadd_rn(__fadd_rn(r[4], r[5]), __fadd_rn(r[6], r[7])));
        total = __fadd_rn(total, s);
    }
    ws[k] = total;
}

// ---------------------------------------------------------------------------
// Kernel 1b: pre-convert codebooks fp32 -> bf16 pairs in per-lane MFMA
// B-fragment order: J = ((((q*16+ch)*4 + w)*8 + ks)*64 + l)*4 + e
// ---------------------------------------------------------------------------
__global__ __launch_bounds__(256) void precvt_kernel(const float* __restrict__ cb,
                                                     unsigned* __restrict__ cbbf) {
    const int j = blockIdx.x * 256 + threadIdx.x;      // < 1048576
    const int e  = j & 3;
    const int l  = (j >> 2) & 63;
    const int ks = (j >> 8) & 7;
    const int w  = (j >> 11) & 3;
    const int ch = (j >> 13) & 15;
    const int q  = j >> 17;
    const int C  = ch * 64 + w * 16 + (l & 15);
    const int g  = l >> 4;
    const int s  = ks * 16 + g * 2 + ((e >> 1) << 3) + (e & 1);
    const float* src = cb + ((size_t)q * KBINS + C) * DDIM + 2 * s;
    cbbf[j] = cvtpk(src[0], src[1]);
}

// ---------------------------------------------------------------------------
// Kernel 2: residual VQ. bf16-MFMA screening, register-double-buffered B with
// pinned issue order + LDS-only barriers, global cross-wave row-max
// thresholds (parity-buffered Mpart), exact fp32 rescoring with inline
// overflow fallback (correct for ANY qcnt). LDS 40,596B raw -> 40,960 ->
// exactly 4 blocks/CU with launch_bounds(256,4); all 750 blocks co-resident.
// ---------------------------------------------------------------------------
template<bool WSCB>
__global__ __launch_bounds__(256, 4) void rvq_kernel(const float* __restrict__ x,
                                                     const float* __restrict__ cb,
                                                     const unsigned* __restrict__ cbbf,
                                                     const float* __restrict__ cbsq_g,
                                                     float* __restrict__ loss,
                                                     float* __restrict__ out) {
    __shared__ __align__(16) float As[RPB][260];       // residual fp32 (33.3KB)
    __shared__ float cbsqs[KBINS];                     // 4KB
    __shared__ float rsq[RPB];
    __shared__ float Mrow_s[RPB];
    __shared__ float Mpart[2][4][RPB];                 // parity-buffered (1KB)
    __shared__ unsigned long long winner[RPB];
    __shared__ int   idxs[RPB];
    __shared__ int   qlist[QMAX];                      // 1.5KB
    __shared__ int   qcnt;
    __shared__ float redpart[4];

    const int tid = threadIdx.x;
    const int r0  = blockIdx.x * RPB;
    const int w   = tid >> 6;          // wave 0..3
    const int l   = tid & 63;
    const int cl  = l & 15;
    const int g   = l >> 4;            // 0..3

    const uint4* cbbf4 = (const uint4*)cbbf;

    if (tid < RPB) rsq[tid] = 0.f;
    barrier_lds();

    // ---- load x (B,D,T) transposed into As[row][d], accumulate ||r||^2 ----
    {
        const int row = tid & 31, dg = tid >> 5;
        const int n = r0 + row, b = n / TLEN, t = n % TLEN;
        const float* xp = x + (size_t)b * (DDIM * TLEN) + t;
        float pr = 0.f;
        #pragma unroll
        for (int dd = 0; dd < DDIM; dd += 8) {
            float v = xp[(size_t)(dd + dg) * TLEN];
            As[row][dd + dg] = v;
            pr = __builtin_fmaf(v, v, pr);
        }
        atomicAdd(&rsq[row], pr);
    }
    barrier_lds();

    float* codes_f = out + (size_t)NBATCH * DDIM * TLEN;

    // B-fragment loader: 8 coalesced dwordx4, one per k-step.
    auto loadB = [&](uint4 (&buf)[8], int q_, int ch_) {
        if constexpr (WSCB) {
            const uint4* p = cbbf4 + ((size_t)((q_ * 16 + ch_) * 4 + w) * 8) * 64 + l;
            #pragma unroll
            for (int ks = 0; ks < 8; ++ks) buf[ks] = p[ks * 64];
        } else {
            const float* cp = cb + ((size_t)q_ * KBINS + ch_ * 64 + w * 16 + cl) * DDIM;
            #pragma unroll
            for (int ks = 0; ks < 8; ++ks) {
                const int d0 = ks * 32 + g * 4;
                float4 v0 = *(const float4*)(cp + d0);
                float4 v1 = *(const float4*)(cp + d0 + 16);
                buf[ks].x = cvtpk(v0.x, v0.y);
                buf[ks].y = cvtpk(v0.z, v0.w);
                buf[ks].z = cvtpk(v1.x, v1.y);
                buf[ks].w = cvtpk(v1.z, v1.w);
            }
        }
    };

    uint4 bufA[8], bufB[8];
    loadB(bufA, 0, 0);                 // prologue: stage 0 chunk 0 in flight
    __builtin_amdgcn_sched_barrier(0);

    for (int q = 0; q < NQ; ++q) {
        const float* cbq = cb + (size_t)q * (KBINS * DDIM);

        // exact fp32 score of (row,col) -> tournament key -> atomicMax winner
        auto exact_score = [&](int row, int col) {
            const float* cp = cbq + (size_t)col * DDIM;
            const float* ar = As[row];
            float dot = 0.f;
            #pragma unroll 16
            for (int d = 0; d < DDIM; d += 4) {
                float4 c4 = *(const float4*)(cp + d);
                float4 a4 = *(const float4*)(ar + d);
                dot = __builtin_fmaf(a4.x, c4.x, dot);
                dot = __builtin_fmaf(a4.y, c4.y, dot);
                dot = __builtin_fmaf(a4.z, c4.z, dot);
                dot = __builtin_fmaf(a4.w, c4.w, dot);
            }
            float sx = __fsub_rn(__fmul_rn(2.f, dot), cbsqs[col]);
            unsigned ub = __float_as_uint(sx);
            ub = (ub & 0x80000000u) ? ~ub : (ub | 0x80000000u);
            unsigned long long key = ((unsigned long long)ub << 10) | (unsigned)(1023 - col);
            atomicMax(&winner[row], key);
        };

        // ---- stage cbsq into LDS + wave-partial max ||c||^2 ----
        float c4m = -INFINITY;
        #pragma unroll
        for (int j = 0; j < 4; ++j) {
            float v = cbsq_g[q * KBINS + tid + j * 256];
            cbsqs[tid + j * 256] = v;
            c4m = fmaxf(c4m, v);
        }
        #pragma unroll
        for (int m = 1; m < 64; m <<= 1) c4m = fmaxf(c4m, __shfl_xor(c4m, m, 64));
        if (l == 0) redpart[w] = c4m;

        // ---- A fragments: residual -> bf16 (register-resident all stage) ----
        Frag af[2][8];
        #pragma unroll
        for (int mt = 0; mt < 2; ++mt)
            #pragma unroll
            for (int ks = 0; ks < 8; ++ks) {
                const float* ap = &As[mt * 16 + cl][ks * 32 + 4 * g];
                float4 x0 = *(const float4*)ap;
                float4 x1 = *(const float4*)(ap + 16);
                af[mt][ks].u.x = cvtpk(x0.x, x0.y);
                af[mt][ks].u.y = cvtpk(x0.z, x0.w);
                af[mt][ks].u.z = cvtpk(x1.x, x1.y);
                af[mt][ks].u.w = cvtpk(x1.z, x1.w);
            }

        if (tid < RPB) { Mrow_s[tid] = -INFINITY; winner[tid] = 0ull; }
        if (tid == 0) qcnt = 0;
        barrier_lds();

        // per-lane register max ||c||^2 (redpart written pre-barrier, safe)
        const float cmax = sqrtf(fmaxf(fmaxf(redpart[0], redpart[1]),
                                       fmaxf(redpart[2], redpart[3])));

        for (int quarter = 0; quarter < 4; ++quarter) {
            const int par = quarter & 1;
            float m_lane[2][4];
            #pragma unroll
            for (int mt = 0; mt < 2; ++mt)
                #pragma unroll
                for (int r = 0; r < 4; ++r) m_lane[mt][r] = -INFINITY;
            unsigned spack[4][2][2];   // 16 VGPRs, static-indexed

            #pragma unroll
            for (int cc = 0; cc < 4; ++cc) {
                const int ch = quarter * 4 + cc;
                uint4 (&cur)[8] = (cc & 1) ? bufB : bufA;
                uint4 (&nxt)[8] = (cc & 1) ? bufA : bufB;

                // prefetch next chunk (wraps to next stage's chunk 0)
                int pq = q, pch = ch + 1;
                if (ch == 15) { pq = (q < NQ - 1) ? q + 1 : q; pch = 0; }
                loadB(nxt, pq, pch);
                __builtin_amdgcn_sched_barrier(0);   // pin: loads issue BEFORE MFMAs

                // ---- 16 MFMAs, 4 independent chains (ks even/odd x 2 tiles) ----
                f32x4 aE0, aO0, aE1, aO1;
                #pragma unroll
                for (int r = 0; r < 4; ++r) { aE0[r] = 0.f; aO0[r] = 0.f; aE1[r] = 0.f; aO1[r] = 0.f; }
                #pragma unroll
                for (int ks = 0; ks < 8; ks += 2) {
                    Frag b0; b0.u = cur[ks];
                    Frag b1; b1.u = cur[ks + 1];
                    aE0 = __builtin_amdgcn_mfma_f32_16x16x32_bf16(af[0][ks].s,     b0.s, aE0, 0, 0, 0);
                    aE1 = __builtin_amdgcn_mfma_f32_16x16x32_bf16(af[1][ks].s,     b0.s, aE1, 0, 0, 0);
                    aO0 = __builtin_amdgcn_mfma_f32_16x16x32_bf16(af[0][ks + 1].s, b1.s, aO0, 0, 0, 0);
                    aO1 = __builtin_amdgcn_mfma_f32_16x16x32_bf16(af[1][ks + 1].s, b1.s, aO1, 0, 0, 0);
                }

                // ---- fold: s = 2*(E+O) - cbsq; running max; truncate-pack ----
                const float sqv = cbsqs[ch * 64 + w * 16 + cl];
                {
                    float s0 = 2.f * (aE0[0] + aO0[0]) - sqv, s1 = 2.f * (aE0[1] + aO0[1]) - sqv;
                    float s2 = 2.f * (aE0[2] + aO0[2]) - sqv, s3 = 2.f * (aE0[3] + aO0[3]) - sqv;
                    m_lane[0][0] = fmaxf(m_lane[0][0], s0);
                    m_lane[0][1] = fmaxf(m_lane[0][1], s1);
                    m_lane[0][2] = fmaxf(m_lane[0][2], s2);
                    m_lane[0][3] = fmaxf(m_lane[0][3], s3);
                    spack[cc][0][0] = (__float_as_uint(s1) & 0xFFFF0000u) | (__float_as_uint(s0) >> 16);
                    spack[cc][0][1] = (__float_as_uint(s3) & 0xFFFF0000u) | (__float_as_uint(s2) >> 16);
                }
                {
                    float s0 = 2.f * (aE1[0] + aO1[0]) - sqv, s1 = 2.f * (aE1[1] + aO1[1]) - sqv;
                    float s2 = 2.f * (aE1[2] + aO1[2]) - sqv, s3 = 2.f * (aE1[3] + aO1[3]) - sqv;
                    m_lane[1][0] = fmaxf(m_lane[1][0], s0);
                    m_lane[1][1] = fmaxf(m_lane[1][1], s1);
                    m_lane[1][2] = fmaxf(m_lane[1][2], s2);
                    m_lane[1][3] = fmaxf(m_lane[1][3], s3);
                    spack[cc][1][0] = (__float_as_uint(s1) & 0xFFFF0000u) | (__float_as_uint(s0) >> 16);
                    spack[cc][1][1] = (__float_as_uint(s3) & 0xFFFF0000u) | (__float_as_uint(s2) >> 16);
                }
            }

            // ---- publish per-wave row maxima (parity-buffered) ----
            #pragma unroll
            for (int m = 1; m <= 8; m <<= 1)
                #pragma unroll
                for (int mt = 0; mt < 2; ++mt)
                    #pragma unroll
                    for (int r = 0; r < 4; ++r)
                        m_lane[mt][r] = fmaxf(m_lane[mt][r], __shfl_xor(m_lane[mt][r], m, 64));
            if (cl == 0) {
                #pragma unroll
                for (int mt = 0; mt < 2; ++mt)
                    #pragma unroll
                    for (int r = 0; r < 4; ++r)
                        Mpart[par][w][mt * 16 + g * 4 + r] = m_lane[mt][r];
            }
            barrier_lds();

            // ---- per-lane redundant thresholds for this lane's 8 scan rows ----
            // benign same-value races on Mrow_s; stale value only lowers thr (safe)
            float thrl[2][4];
            #pragma unroll
            for (int mt = 0; mt < 2; ++mt)
                #pragma unroll
                for (int jj = 0; jj < 4; ++jj) {
                    const int r = mt * 16 + g * 4 + jj;
                    float M = fmaxf(fmaxf(Mpart[par][0][r], Mpart[par][1][r]),
                                    fmaxf(Mpart[par][2][r], Mpart[par][3][r]));
                    float Mr = fmaxf(Mrow_s[r], M);
                    Mrow_s[r] = Mr;
                    float margin = 0.02f * sqrtf(rsq[r]) * cmax
                                 + 0.006f * fabsf(Mr) + 0.25f;
                    thrl[mt][jj] = Mr - margin;
                }

            // ---- scan quarter's scores, enqueue candidates ----
            // overflow-safe: if qlist is full, rescore the candidate inline.
            #pragma unroll
            for (int cc = 0; cc < 4; ++cc) {
                const int colc = (quarter * 4 + cc) * 64 + w * 16 + cl;
                #pragma unroll
                for (int mt = 0; mt < 2; ++mt)
                    #pragma unroll
                    for (int pr = 0; pr < 2; ++pr) {
                        unsigned u = spack[cc][mt][pr];
                        float slo = __uint_as_float(u << 16);
                        float shi = __uint_as_float(u & 0xFFFF0000u);
                        if (slo >= thrl[mt][pr * 2]) {
                            const int row = mt * 16 + g * 4 + pr * 2;
                            int p = atomicAdd(&qcnt, 1);
                            if (__builtin_expect(p < QMAX, 1)) qlist[p] = (row << 10) | colc;
                            else exact_score(row, colc);
                        }
                        if (shi >= thrl[mt][pr * 2 + 1]) {
                            const int row = mt * 16 + g * 4 + pr * 2 + 1;
                            int p = atomicAdd(&qcnt, 1);
                            if (__builtin_expect(p < QMAX, 1)) qlist[p] = (row << 10) | colc;
                            else exact_score(row, colc);
                        }
                    }
            }
        }
        barrier_lds();

        // ---- exact rescore (sequential-K fp32, reference ordering) ----
        {
            int nc = qcnt < QMAX ? qcnt : QMAX;
            for (int i = tid; i < nc; i += 256) {
                const int rc = qlist[i];
                exact_score(rc >> 10, rc & 1023);
            }
        }
        barrier_lds();
        if (tid < RPB) {
            int col = 1023 - (int)(winner[tid] & 1023ull);
            idxs[tid] = col;
            codes_f[(size_t)q * NROWS + r0 + tid] = (float)col;
            rsq[tid] = 0.f;
        }
        barrier_lds();

        // ---- update: tmp=c-r; qst=r+tmp; r=r-qst (reference rounding) ----
        {
            const int row = tid & 31, d0 = (tid >> 5) * 32;
            const float* crow = cbq + (size_t)idxs[row] * DDIM + d0;
            float* arow = &As[row][d0];
            float lp = 0.f, pr = 0.f;
            #pragma unroll
            for (int u = 0; u < 32; u += 4) {
                const float4 c4 = *(const float4*)(crow + u);
                const float4 a4 = *(const float4*)(arow + u);
                const float cv[4] = { c4.x, c4.y, c4.z, c4.w };
                const float rv[4] = { a4.x, a4.y, a4.z, a4.w };
                float rn[4];
                #pragma unroll
                for (int v = 0; v < 4; ++v) {
                    const float tmp = __fsub_rn(cv[v], rv[v]);
                    const float qs  = __fadd_rn(rv[v], tmp);
                    rn[v] = __fsub_rn(rv[v], qs);
                    lp = __builtin_fmaf(tmp, tmp, lp);
                    pr = __builtin_fmaf(rn[v], rn[v], pr);
                }
                float4 o4; o4.x = rn[0]; o4.y = rn[1]; o4.z = rn[2]; o4.w = rn[3];
                *(float4*)(arow + u) = o4;
            }
            #pragma unroll
            for (int m = 1; m < 64; m <<= 1) lp += __shfl_xor(lp, m, 64);
            if (l == 0) atomicAdd(&loss[q], lp);
            atomicAdd(&rsq[row], pr);
        }
        barrier_lds();
    }

    // ---- quantized output: x - final residual (telescoped) ----
    {
        const int row = tid & 31, dg = tid >> 5;
        const int n = r0 + row, b = n / TLEN, t = n % TLEN;
        const float* xp = x + (size_t)b * (DDIM * TLEN) + t;
        float* op = out + (size_t)b * (DDIM * TLEN) + t;
        #pragma unroll
        for (int u = 0; u < 32; ++u) {
            const int d = dg * 32 + u;
            op[(size_t)d * TLEN] = __fsub_rn(xp[(size_t)d * TLEN], As[row][d]);
        }
    }
}

// ---------------------------------------------------------------------------
// Kernel 3: penalty = mean over stages of (loss_q / (N*D))
// ---------------------------------------------------------------------------
__global__ void finalize_kernel(const float* __restrict__ loss, float* __restrict__ out) {
    if (threadIdx.x == 0 && blockIdx.x == 0) {
        float s = 0.f;
        for (int q = 0; q < NQ; ++q) s += loss[q] / (float)(NROWS * DDIM);
        out[(size_t)NBATCH * DDIM * TLEN + (size_t)NQ * NROWS] = s / (float)NQ;
    }
}

extern "C" void kernel_launch(void* const* d_in, const int* in_sizes, int n_in,
                              void* d_out, int out_size, void* d_ws, size_t ws_size,
                              hipStream_t stream) {
    const float* x  = (const float*)d_in[0];
    const float* cb = (const float*)d_in[1];
    float* out  = (float*)d_out;
    float* ws   = (float*)d_ws;
    float* cbsq = ws;                           // 8192 floats
    float* loss = ws + NQ * KBINS;              // 8 floats
    unsigned* cbbf = (unsigned*)(ws + 8224);    // 1048576 u32 (bf16 frags, lane-ordered)
    const bool wsbf = ws_size >= (size_t)(8224 + (size_t)NQ * KBINS * DDIM / 2) * 4;

    hipLaunchKernelGGL(cbsq_kernel, dim3((NQ * KBINS) / 256), dim3(256), 0, stream, cb, ws);
    if (wsbf) {
        hipLaunchKernelGGL(precvt_kernel, dim3((NQ * KBINS * DDIM / 2) / 256), dim3(256),
                           0, stream, cb, cbbf);
        hipLaunchKernelGGL((rvq_kernel<true>), dim3(NROWS / RPB), dim3(256), 0, stream,
                           x, cb, cbbf, cbsq, loss, out);
    } else {
        hipLaunchKernelGGL((rvq_kernel<false>), dim3(NROWS / RPB), dim3(256), 0, stream,
                           x, cb, cbbf, cbsq, loss, out);
    }
    hipLaunchKernelGGL(finalize_kernel, dim3(1), dim3(64), 0, stream, loss, out);
}

// Round 3
// 441.934 us; speedup vs baseline: 2.5851x; 2.5851x over previous
//
#include <hip/hip_runtime.h>
#include <math.h>

#define NBATCH 16
#define DDIM   256
#define TLEN   1500
#define NROWS  (NBATCH * TLEN)     // 24000
#define KBINS  1024
#define NQ     8
#define RPB    32                  // rows per block
#define QMAX   384

typedef float  f32x4  __attribute__((ext_vector_type(4)));
typedef short  short8 __attribute__((ext_vector_type(8)));
union Frag { uint4 u; short8 s; };

__device__ __forceinline__ unsigned cvtpk(float a, float b) {
    unsigned r;
    asm("v_cvt_pk_bf16_f32 %0, %1, %2" : "=v"(r) : "v"(a), "v"(b));
    return r;
}

// LDS-only barrier: waits ds ops, does NOT drain vmcnt -> global prefetch
// stays in flight across phase boundaries. All inter-wave comms here are LDS.
__device__ __forceinline__ void barrier_lds() {
    __builtin_amdgcn_sched_barrier(0);
    asm volatile("s_waitcnt lgkmcnt(0)" ::: "memory");
    __builtin_amdgcn_s_barrier();
    __builtin_amdgcn_sched_barrier(0);
}

// ---------------------------------------------------------------------------
// Kernel 1: cbsq[q][k] = numpy-pairwise sum(c*c) over D=256  (+ zero losses)
// ---------------------------------------------------------------------------
__global__ __launch_bounds__(256) void cbsq_kernel(const float* __restrict__ cb,
                                                   float* __restrict__ ws) {
    const int k = blockIdx.x * 256 + threadIdx.x;      // 0..8191
    if (blockIdx.x == 0 && threadIdx.x < NQ) ws[NQ * KBINS + threadIdx.x] = 0.f;
    if (k >= NQ * KBINS) return;
    const float* p = cb + (size_t)k * DDIM;
    float total = 0.f;
    #pragma unroll
    for (int h = 0; h < 2; ++h) {
        const float* ph = p + h * 128;
        float r[8];
        #pragma unroll
        for (int j = 0; j < 8; ++j) { float v = ph[j]; r[j] = __fmul_rn(v, v); }
        for (int i = 8; i < 128; i += 8) {
            #pragma unroll
            for (int j = 0; j < 8; ++j) {
                float v = ph[i + j];
                r[j] = __fadd_rn(r[j], __fmul_rn(v, v));
            }
        }
        float s = __fadd_rn(__fadd_rn(__fadd_rn(r[0], r[1]), __fadd_rn(r[2], r[3])),
                            __fadd_rn(__fadd_rn(r[4], r[5]), __fadd_rn(r[6], r[7])));
        total = __fadd_rn(total, s);
    }
    ws[k] = total;
}

// ---------------------------------------------------------------------------
// Kernel 1b: pre-convert codebooks fp32 -> bf16 pairs in per-lane MFMA
// B-fragment order: J = ((((q*16+ch)*4 + w)*8 + ks)*64 + l)*4 + e
// ---------------------------------------------------------------------------
__global__ __launch_bounds__(256) void precvt_kernel(const float* __restrict__ cb,
                                                     unsigned* __restrict__ cbbf) {
    const int j = blockIdx.x * 256 + threadIdx.x;      // < 1048576
    const int e  = j & 3;
    const int l  = (j >> 2) & 63;
    const int ks = (j >> 8) & 7;
    const int w  = (j >> 11) & 3;
    const int ch = (j >> 13) & 15;
    const int q  = j >> 17;
    const int C  = ch * 64 + w * 16 + (l & 15);
    const int g  = l >> 4;
    const int s  = ks * 16 + g * 2 + ((e >> 1) << 3) + (e & 1);
    const float* src = cb + ((size_t)q * KBINS + C) * DDIM + 2 * s;
    cbbf[j] = cvtpk(src[0], src[1]);
}

// ---------------------------------------------------------------------------
// Kernel 2: residual VQ. bf16-MFMA screening, register-double-buffered B with
// pinned issue order + LDS-only barriers, global cross-wave row-max
// thresholds (parity-buffered Mpart), exact fp32 rescoring. Queue overflow
// is handled by a per-row flag + full-row repair pass (exact for any qcnt,
// zero register pressure in the hot loop). LDS total 40,600B -> 40,960
// block size; with 128 VGPR (launch_bounds(256,2) cap) hardware fits
// 4 blocks/CU = 16 waves/CU; all 750 blocks co-resident.
// ---------------------------------------------------------------------------
template<bool WSCB>
__global__ __launch_bounds__(256, 2) void rvq_kernel(const float* __restrict__ x,
                                                     const float* __restrict__ cb,
                                                     const unsigned* __restrict__ cbbf,
                                                     const float* __restrict__ cbsq_g,
                                                     float* __restrict__ loss,
                                                     float* __restrict__ out) {
    __shared__ __align__(16) float As[RPB][260];       // residual fp32 (33.3KB)
    __shared__ float cbsqs[KBINS];                     // 4KB
    __shared__ float rsq[RPB];
    __shared__ float Mrow_s[RPB];
    __shared__ float Mpart[2][4][RPB];                 // parity-buffered (1KB)
    __shared__ unsigned long long winner[RPB];
    __shared__ int   idxs[RPB];
    __shared__ int   qlist[QMAX];                      // 1.5KB
    __shared__ int   qcnt;
    __shared__ unsigned ovf;                           // rows whose cands overflowed
    __shared__ float redpart[4];

    const int tid = threadIdx.x;
    const int r0  = blockIdx.x * RPB;
    const int w   = tid >> 6;          // wave 0..3
    const int l   = tid & 63;
    const int cl  = l & 15;
    const int g   = l >> 4;            // 0..3

    const uint4* cbbf4 = (const uint4*)cbbf;

    if (tid < RPB) rsq[tid] = 0.f;
    barrier_lds();

    // ---- load x (B,D,T) transposed into As[row][d], accumulate ||r||^2 ----
    {
        const int row = tid & 31, dg = tid >> 5;
        const int n = r0 + row, b = n / TLEN, t = n % TLEN;
        const float* xp = x + (size_t)b * (DDIM * TLEN) + t;
        float pr = 0.f;
        #pragma unroll
        for (int dd = 0; dd < DDIM; dd += 8) {
            float v = xp[(size_t)(dd + dg) * TLEN];
            As[row][dd + dg] = v;
            pr = __builtin_fmaf(v, v, pr);
        }
        atomicAdd(&rsq[row], pr);
    }
    barrier_lds();

    float* codes_f = out + (size_t)NBATCH * DDIM * TLEN;

    // B-fragment loader: 8 coalesced dwordx4, one per k-step.
    auto loadB = [&](uint4 (&buf)[8], int q_, int ch_) {
        if constexpr (WSCB) {
            const uint4* p = cbbf4 + ((size_t)((q_ * 16 + ch_) * 4 + w) * 8) * 64 + l;
            #pragma unroll
            for (int ks = 0; ks < 8; ++ks) buf[ks] = p[ks * 64];
        } else {
            const float* cp = cb + ((size_t)q_ * KBINS + ch_ * 64 + w * 16 + cl) * DDIM;
            #pragma unroll
            for (int ks = 0; ks < 8; ++ks) {
                const int d0 = ks * 32 + g * 4;
                float4 v0 = *(const float4*)(cp + d0);
                float4 v1 = *(const float4*)(cp + d0 + 16);
                buf[ks].x = cvtpk(v0.x, v0.y);
                buf[ks].y = cvtpk(v0.z, v0.w);
                buf[ks].z = cvtpk(v1.x, v1.y);
                buf[ks].w = cvtpk(v1.z, v1.w);
            }
        }
    };

    uint4 bufA[8], bufB[8];
    loadB(bufA, 0, 0);                 // prologue: stage 0 chunk 0 in flight
    __builtin_amdgcn_sched_barrier(0);

    for (int q = 0; q < NQ; ++q) {
        const float* cbq = cb + (size_t)q * (KBINS * DDIM);

        // exact fp32 score of (row,col) -> tournament key -> atomicMax winner
        auto exact_score = [&](int row, int col) {
            const float* cp = cbq + (size_t)col * DDIM;
            const float* ar = As[row];
            float dot = 0.f;
            #pragma unroll 16
            for (int d = 0; d < DDIM; d += 4) {
                float4 c4 = *(const float4*)(cp + d);
                float4 a4 = *(const float4*)(ar + d);
                dot = __builtin_fmaf(a4.x, c4.x, dot);
                dot = __builtin_fmaf(a4.y, c4.y, dot);
                dot = __builtin_fmaf(a4.z, c4.z, dot);
                dot = __builtin_fmaf(a4.w, c4.w, dot);
            }
            float sx = __fsub_rn(__fmul_rn(2.f, dot), cbsqs[col]);
            unsigned ub = __float_as_uint(sx);
            ub = (ub & 0x80000000u) ? ~ub : (ub | 0x80000000u);
            unsigned long long key = ((unsigned long long)ub << 10) | (unsigned)(1023 - col);
            atomicMax(&winner[row], key);
        };

        // ---- stage cbsq into LDS + wave-partial max ||c||^2 ----
        float c4m = -INFINITY;
        #pragma unroll
        for (int j = 0; j < 4; ++j) {
            float v = cbsq_g[q * KBINS + tid + j * 256];
            cbsqs[tid + j * 256] = v;
            c4m = fmaxf(c4m, v);
        }
        #pragma unroll
        for (int m = 1; m < 64; m <<= 1) c4m = fmaxf(c4m, __shfl_xor(c4m, m, 64));
        if (l == 0) redpart[w] = c4m;

        // ---- A fragments: residual -> bf16 (register-resident all stage) ----
        Frag af[2][8];
        #pragma unroll
        for (int mt = 0; mt < 2; ++mt)
            #pragma unroll
            for (int ks = 0; ks < 8; ++ks) {
                const float* ap = &As[mt * 16 + cl][ks * 32 + 4 * g];
                float4 x0 = *(const float4*)ap;
                float4 x1 = *(const float4*)(ap + 16);
                af[mt][ks].u.x = cvtpk(x0.x, x0.y);
                af[mt][ks].u.y = cvtpk(x0.z, x0.w);
                af[mt][ks].u.z = cvtpk(x1.x, x1.y);
                af[mt][ks].u.w = cvtpk(x1.z, x1.w);
            }

        if (tid < RPB) { Mrow_s[tid] = -INFINITY; winner[tid] = 0ull; }
        if (tid == 0) { qcnt = 0; ovf = 0u; }
        barrier_lds();

        // per-lane register max ||c||^2 (redpart written pre-barrier, safe)
        const float cmax = sqrtf(fmaxf(fmaxf(redpart[0], redpart[1]),
                                       fmaxf(redpart[2], redpart[3])));

        for (int quarter = 0; quarter < 4; ++quarter) {
            const int par = quarter & 1;
            float m_lane[2][4];
            #pragma unroll
            for (int mt = 0; mt < 2; ++mt)
                #pragma unroll
                for (int r = 0; r < 4; ++r) m_lane[mt][r] = -INFINITY;
            unsigned spack[4][2][2];   // 16 VGPRs, static-indexed

            #pragma unroll
            for (int cc = 0; cc < 4; ++cc) {
                const int ch = quarter * 4 + cc;
                uint4 (&cur)[8] = (cc & 1) ? bufB : bufA;
                uint4 (&nxt)[8] = (cc & 1) ? bufA : bufB;

                // prefetch next chunk (wraps to next stage's chunk 0)
                int pq = q, pch = ch + 1;
                if (ch == 15) { pq = (q < NQ - 1) ? q + 1 : q; pch = 0; }
                loadB(nxt, pq, pch);
                __builtin_amdgcn_sched_barrier(0);   // pin: loads issue BEFORE MFMAs

                // ---- 16 MFMAs, 4 independent chains (ks even/odd x 2 tiles) ----
                f32x4 aE0, aO0, aE1, aO1;
                #pragma unroll
                for (int r = 0; r < 4; ++r) { aE0[r] = 0.f; aO0[r] = 0.f; aE1[r] = 0.f; aO1[r] = 0.f; }
                #pragma unroll
                for (int ks = 0; ks < 8; ks += 2) {
                    Frag b0; b0.u = cur[ks];
                    Frag b1; b1.u = cur[ks + 1];
                    aE0 = __builtin_amdgcn_mfma_f32_16x16x32_bf16(af[0][ks].s,     b0.s, aE0, 0, 0, 0);
                    aE1 = __builtin_amdgcn_mfma_f32_16x16x32_bf16(af[1][ks].s,     b0.s, aE1, 0, 0, 0);
                    aO0 = __builtin_amdgcn_mfma_f32_16x16x32_bf16(af[0][ks + 1].s, b1.s, aO0, 0, 0, 0);
                    aO1 = __builtin_amdgcn_mfma_f32_16x16x32_bf16(af[1][ks + 1].s, b1.s, aO1, 0, 0, 0);
                }

                // ---- fold: s = 2*(E+O) - cbsq; running max; truncate-pack ----
                const float sqv = cbsqs[ch * 64 + w * 16 + cl];
                {
                    float s0 = 2.f * (aE0[0] + aO0[0]) - sqv, s1 = 2.f * (aE0[1] + aO0[1]) - sqv;
                    float s2 = 2.f * (aE0[2] + aO0[2]) - sqv, s3 = 2.f * (aE0[3] + aO0[3]) - sqv;
                    m_lane[0][0] = fmaxf(m_lane[0][0], s0);
                    m_lane[0][1] = fmaxf(m_lane[0][1], s1);
                    m_lane[0][2] = fmaxf(m_lane[0][2], s2);
                    m_lane[0][3] = fmaxf(m_lane[0][3], s3);
                    spack[cc][0][0] = (__float_as_uint(s1) & 0xFFFF0000u) | (__float_as_uint(s0) >> 16);
                    spack[cc][0][1] = (__float_as_uint(s3) & 0xFFFF0000u) | (__float_as_uint(s2) >> 16);
                }
                {
                    float s0 = 2.f * (aE1[0] + aO1[0]) - sqv, s1 = 2.f * (aE1[1] + aO1[1]) - sqv;
                    float s2 = 2.f * (aE1[2] + aO1[2]) - sqv, s3 = 2.f * (aE1[3] + aO1[3]) - sqv;
                    m_lane[1][0] = fmaxf(m_lane[1][0], s0);
                    m_lane[1][1] = fmaxf(m_lane[1][1], s1);
                    m_lane[1][2] = fmaxf(m_lane[1][2], s2);
                    m_lane[1][3] = fmaxf(m_lane[1][3], s3);
                    spack[cc][1][0] = (__float_as_uint(s1) & 0xFFFF0000u) | (__float_as_uint(s0) >> 16);
                    spack[cc][1][1] = (__float_as_uint(s3) & 0xFFFF0000u) | (__float_as_uint(s2) >> 16);
                }
            }

            // ---- publish per-wave row maxima (parity-buffered) ----
            #pragma unroll
            for (int m = 1; m <= 8; m <<= 1)
                #pragma unroll
                for (int mt = 0; mt < 2; ++mt)
                    #pragma unroll
                    for (int r = 0; r < 4; ++r)
                        m_lane[mt][r] = fmaxf(m_lane[mt][r], __shfl_xor(m_lane[mt][r], m, 64));
            if (cl == 0) {
                #pragma unroll
                for (int mt = 0; mt < 2; ++mt)
                    #pragma unroll
                    for (int r = 0; r < 4; ++r)
                        Mpart[par][w][mt * 16 + g * 4 + r] = m_lane[mt][r];
            }
            barrier_lds();

            // ---- per-lane redundant thresholds for this lane's 8 scan rows ----
            // benign same-value races on Mrow_s; stale value only lowers thr (safe)
            float thrl[2][4];
            #pragma unroll
            for (int mt = 0; mt < 2; ++mt)
                #pragma unroll
                for (int jj = 0; jj < 4; ++jj) {
                    const int r = mt * 16 + g * 4 + jj;
                    float M = fmaxf(fmaxf(Mpart[par][0][r], Mpart[par][1][r]),
                                    fmaxf(Mpart[par][2][r], Mpart[par][3][r]));
                    float Mr = fmaxf(Mrow_s[r], M);
                    Mrow_s[r] = Mr;
                    float margin = 0.02f * sqrtf(rsq[r]) * cmax
                                 + 0.006f * fabsf(Mr) + 0.25f;
                    thrl[mt][jj] = Mr - margin;
                }

            // ---- scan quarter's scores, enqueue candidates ----
            // overflow-safe: flag the row; repair pass rescans it exactly.
            #pragma unroll
            for (int cc = 0; cc < 4; ++cc) {
                const int colc = (quarter * 4 + cc) * 64 + w * 16 + cl;
                #pragma unroll
                for (int mt = 0; mt < 2; ++mt)
                    #pragma unroll
                    for (int pr = 0; pr < 2; ++pr) {
                        unsigned u = spack[cc][mt][pr];
                        float slo = __uint_as_float(u << 16);
                        float shi = __uint_as_float(u & 0xFFFF0000u);
                        if (slo >= thrl[mt][pr * 2]) {
                            const int row = mt * 16 + g * 4 + pr * 2;
                            int p = atomicAdd(&qcnt, 1);
                            if (__builtin_expect(p < QMAX, 1)) qlist[p] = (row << 10) | colc;
                            else atomicOr(&ovf, 1u << row);
                        }
                        if (shi >= thrl[mt][pr * 2 + 1]) {
                            const int row = mt * 16 + g * 4 + pr * 2 + 1;
                            int p = atomicAdd(&qcnt, 1);
                            if (__builtin_expect(p < QMAX, 1)) qlist[p] = (row << 10) | colc;
                            else atomicOr(&ovf, 1u << row);
                        }
                    }
            }
        }
        barrier_lds();

        // ---- exact rescore (sequential-K fp32, reference ordering) ----
        {
            int nc = qcnt < QMAX ? qcnt : QMAX;
            for (int i = tid; i < nc; i += 256) {
                const int rc = qlist[i];
                exact_score(rc >> 10, rc & 1023);
            }
            // repair pass: rows whose candidates overflowed -> full rescan.
            // (never taken in practice; exactness guarantee for any qcnt)
            if (__builtin_expect(ovf != 0u, 0)) {
                unsigned om = ovf;
                while (om) {
                    const int row = __ffs(om) - 1;
                    om &= om - 1;
                    for (int c = tid; c < KBINS; c += 256) exact_score(row, c);
                }
            }
        }
        barrier_lds();
        if (tid < RPB) {
            int col = 1023 - (int)(winner[tid] & 1023ull);
            idxs[tid] = col;
            codes_f[(size_t)q * NROWS + r0 + tid] = (float)col;
            rsq[tid] = 0.f;
        }
        barrier_lds();

        // ---- update: tmp=c-r; qst=r+tmp; r=r-qst (reference rounding) ----
        {
            const int row = tid & 31, d0 = (tid >> 5) * 32;
            const float* crow = cbq + (size_t)idxs[row] * DDIM + d0;
            float* arow = &As[row][d0];
            float lp = 0.f, pr = 0.f;
            #pragma unroll
            for (int u = 0; u < 32; u += 4) {
                const float4 c4 = *(const float4*)(crow + u);
                const float4 a4 = *(const float4*)(arow + u);
                const float cv[4] = { c4.x, c4.y, c4.z, c4.w };
                const float rv[4] = { a4.x, a4.y, a4.z, a4.w };
                float rn[4];
                #pragma unroll
                for (int v = 0; v < 4; ++v) {
                    const float tmp = __fsub_rn(cv[v], rv[v]);
                    const float qs  = __fadd_rn(rv[v], tmp);
                    rn[v] = __fsub_rn(rv[v], qs);
                    lp = __builtin_fmaf(tmp, tmp, lp);
                    pr = __builtin_fmaf(rn[v], rn[v], pr);
                }
                float4 o4; o4.x = rn[0]; o4.y = rn[1]; o4.z = rn[2]; o4.w = rn[3];
                *(float4*)(arow + u) = o4;
            }
            #pragma unroll
            for (int m = 1; m < 64; m <<= 1) lp += __shfl_xor(lp, m, 64);
            if (l == 0) atomicAdd(&loss[q], lp);
            atomicAdd(&rsq[row], pr);
        }
        barrier_lds();
    }

    // ---- quantized output: x - final residual (telescoped) ----
    {
        const int row = tid & 31, dg = tid >> 5;
        const int n = r0 + row, b = n / TLEN, t = n % TLEN;
        const float* xp = x + (size_t)b * (DDIM * TLEN) + t;
        float* op = out + (size_t)b * (DDIM * TLEN) + t;
        #pragma unroll
        for (int u = 0; u < 32; ++u) {
            const int d = dg * 32 + u;
            op[(size_t)d * TLEN] = __fsub_rn(xp[(size_t)d * TLEN], As[row][d]);
        }
    }
}

// ---------------------------------------------------------------------------
// Kernel 3: penalty = mean over stages of (loss_q / (N*D))
// ---------------------------------------------------------------------------
__global__ void finalize_kernel(const float* __restrict__ loss, float* __restrict__ out) {
    if (threadIdx.x == 0 && blockIdx.x == 0) {
        float s = 0.f;
        for (int q = 0; q < NQ; ++q) s += loss[q] / (float)(NROWS * DDIM);
        out[(size_t)NBATCH * DDIM * TLEN + (size_t)NQ * NROWS] = s / (float)NQ;
    }
}

extern "C" void kernel_launch(void* const* d_in, const int* in_sizes, int n_in,
                              void* d_out, int out_size, void* d_ws, size_t ws_size,
                              hipStream_t stream) {
    const float* x  = (const float*)d_in[0];
    const float* cb = (const float*)d_in[1];
    float* out  = (float*)d_out;
    float* ws   = (float*)d_ws;
    float* cbsq = ws;                           // 8192 floats
    float* loss = ws + NQ * KBINS;              // 8 floats
    unsigned* cbbf = (unsigned*)(ws + 8224);    // 1048576 u32 (bf16 frags, lane-ordered)
    const bool wsbf = ws_size >= (size_t)(8224 + (size_t)NQ * KBINS * DDIM / 2) * 4;

    hipLaunchKernelGGL(cbsq_kernel, dim3((NQ * KBINS) / 256), dim3(256), 0, stream, cb, ws);
    if (wsbf) {
        hipLaunchKernelGGL(precvt_kernel, dim3((NQ * KBINS * DDIM / 2) / 256), dim3(256),
                           0, stream, cb, cbbf);
        hipLaunchKernelGGL((rvq_kernel<true>), dim3(NROWS / RPB), dim3(256), 0, stream,
                           x, cb, cbbf, cbsq, loss, out);
    } else {
        hipLaunchKernelGGL((rvq_kernel<false>), dim3(NROWS / RPB), dim3(256), 0, stream,
                           x, cb, cbbf, cbsq, loss, out);
    }
    hipLaunchKernelGGL(finalize_kernel, dim3(1), dim3(64), 0, stream, loss, out);
}